// Round 12
// baseline (525.347 us; speedup 1.0000x reference)
//
#include <hip/hip_runtime.h>
#include <hip/hip_bf16.h>
#include <math.h>

// Problem constants
#define NB   256      // batch
#define ML   31       // MAX_LEN
#define NT   30       // T = MAX_LEN-1 decode steps
#define NV   10000    // vocab
#define NH   512      // hidden
#define NE   512      // embed
#define NG   2048     // 4*H gates
#define NTILES_N 79   // ceil(NV/128)

// Output layout (floats): preds (256,31,10000) | target (256,30) | dec_len (256,)
#define OFF_TGT  (256LL*31LL*10000LL)
#define OFF_DEC  (OFF_TGT + 256LL*30LL)
#define PRED_B   (31LL*10000LL)

typedef __attribute__((ext_vector_type(8))) short bf16x8;
typedef __attribute__((ext_vector_type(4))) float f32x4;

__device__ inline unsigned short f2bf(float f) {
    unsigned int x = __float_as_uint(f);
    unsigned int r = x + 0x7FFFu + ((x >> 16) & 1u);   // RNE
    return (unsigned short)(r >> 16);
}
__device__ inline float bf2f(unsigned short u) {
    return __uint_as_float((unsigned int)u << 16);
}

__device__ inline void gl2lds16(const void* g, void* l) {
    __builtin_amdgcn_global_load_lds(
        (const __attribute__((address_space(1))) unsigned int*)g,
        (__attribute__((address_space(3))) unsigned int*)l, 16, 0, 0);
}

// ---------- sort: stable descending argsort + counts + zero flags/tilecnt -----
__global__ void sort_k(const int* __restrict__ lens, int* __restrict__ order,
                       int* __restrict__ cnt, int* __restrict__ start,
                       int* __restrict__ flags, float* __restrict__ out_dec) {
    __shared__ int sd[NB];
    int i = threadIdx.x;
    flags[i] = 0;
    if (i == 0) flags[256] = 0;      // tile work-queue counter
    int li = lens[i];
    int r = 0;
    for (int j = 0; j < NB; j++) {
        int lj = lens[j];
        r += (lj > li) || (lj == li && j < i);
    }
    order[r] = i;
    out_dec[r] = (float)(li - 1);
    sd[r] = li - 1;
    __syncthreads();
    if (i < NT) {
        int c = 0;
        for (int b = 0; b < NB; b++) c += (sd[b] > i);
        cnt[i] = c;
    }
    __syncthreads();
    if (i == 0) {
        int s = 0;
        for (int t = 0; t < NT; t++) { start[t] = s; s += cnt[t]; }
        start[NT] = s;                 // n_active
    }
}

// ---------- gather sorted rows (bf16 image), emit target ----------------------
__global__ void gather_k(const float* __restrict__ gimg, const int* __restrict__ w_in,
                         const int* __restrict__ order,
                         unsigned short* __restrict__ g_sb, int* __restrict__ wsort,
                         float* __restrict__ out_tgt) {
    int r = blockIdx.x, tid = threadIdx.x;
    int o = order[r];
    for (int e = tid; e < NE; e += 256)
        g_sb[r * NE + e] = f2bf(gimg[o * NE + e]);
    if (tid < ML) wsort[r * ML + tid] = w_in[o * ML + tid];
    if (tid < NT) out_tgt[r * NT + tid] = (float)w_in[o * ML + tid + 1];
}

// ---------- compact active-row lists + zero rowsum ----------------------------
__global__ void rowlist_k(const int* __restrict__ wsort, const int* __restrict__ cnt,
                          const int* __restrict__ start,
                          int* __restrict__ rowlist, int* __restrict__ rowwc,
                          float* __restrict__ rowsum) {
    int t = blockIdx.x, b = threadIdx.x;
    rowsum[t * 256 + b] = 0.f;
    if (b < cnt[t]) {
        int pos = start[t] + b;
        rowlist[pos] = t * 256 + b;
        rowwc[pos] = wsort[b * ML + t];
    }
}

// ---------- fused preamble conversions ----------------------------------------
__global__ void prep_k(const float* __restrict__ W_ih, const float* __restrict__ W_hh,
                       const float* __restrict__ W_out, const float* __restrict__ emb,
                       unsigned short* __restrict__ Wxl, unsigned short* __restrict__ Wxb,
                       unsigned short* __restrict__ Wob, unsigned short* __restrict__ embb,
                       unsigned short* __restrict__ Wimg2) {
    int bid = blockIdx.x, tid = threadIdx.x;
    if (bid < 2048) {
        int koff = (bid < 1024) ? 0 : NE;
        unsigned short* dst = (bid < 1024) ? Wxl : Wxb;
        int gid = ((bid & 1023) << 8) + tid;        // 2048*128 float4 chunks
        int j = gid >> 7, k4 = gid & 127;
        float4 v = *(const float4*)(W_ih + (size_t)j * (2 * NE) + koff + k4 * 4);
        ushort4 o;
        o.x = f2bf(v.x); o.y = f2bf(v.y); o.z = f2bf(v.z); o.w = f2bf(v.w);
        *(ushort4*)(dst + (size_t)j * NE + k4 * 4) = o;
    } else if (bid < 12048) {
        const float* src = (bid < 7048) ? W_out : emb;
        unsigned short* dst = (bid < 7048) ? Wob : embb;
        int gid = ((bid < 7048 ? bid - 2048 : bid - 7048) << 8) + tid;
        float4 v = ((const float4*)src)[gid];
        ushort4 o;
        o.x = f2bf(v.x); o.y = f2bf(v.y); o.z = f2bf(v.z); o.w = f2bf(v.w);
        ((ushort4*)dst)[gid] = o;
    } else {
        int gid = ((bid - 12048) << 8) + tid;       // 131072 = 16s*128R*16kt*4hi
        int hi = gid & 3, kt = (gid >> 2) & 15, R = (gid >> 6) & 127, s = gid >> 13;
        int q = R >> 5, ct = (R >> 4) & 1, lo = R & 15;
        int col = q * 512 + s * 32 + ct * 16 + lo;
        int k = kt * 32 + hi * 8;
        const float* src = W_hh + (size_t)col * NH + k;
        __align__(16) unsigned short o[8];
#pragma unroll
        for (int j = 0; j < 8; ++j) o[j] = f2bf(src[j]);
        int ba = (R << 10) + ((kt * 64 + hi * 16) ^ ((lo & 7) << 4));
        *(uint4*)((char*)Wimg2 + ((size_t)s << 17) + ba) = *(const uint4*)o;
    }
}

// ---------- small fp32-out GEMM for gx (B-panel-once, A direct) ---------------
__launch_bounds__(256)
__global__ void gxgemm(const unsigned short* __restrict__ Abf,
                       const unsigned short* __restrict__ Bbf,
                       const float* __restrict__ bias1, const float* __restrict__ bias2,
                       float* __restrict__ outf) {
    __shared__ __align__(16) char Bs[131072];   // [128][512] bf16, XOR-swizzled
    int m0 = blockIdx.y * 128, n0 = blockIdx.x * 128;
    int tid = threadIdx.x;
    int lane = tid & 63, w = tid >> 6;
    int wy = w >> 1, wx = w & 1;

#pragma unroll 4
    for (int p = 0; p < 32; ++p) {
        int row = (tid >> 6) + (p << 2);
        uint4 v = *(const uint4*)(Bbf + ((size_t)(n0 + row) << 9) + ((tid & 63) << 3));
        int ba = (row << 10) + ((tid & 63) << 4); ba ^= (row & 7) << 4;
        *(uint4*)(Bs + ba) = v;
    }
    const unsigned short* aptr[4];
#pragma unroll
    for (int rt = 0; rt < 4; ++rt)
        aptr[rt] = Abf + ((size_t)(m0 + (wy << 6) + (rt << 4) + (lane & 15)) << 9);

    f32x4 acc[4][4];
#pragma unroll
    for (int i = 0; i < 4; ++i)
#pragma unroll
        for (int j = 0; j < 4; ++j) acc[i][j] = (f32x4){0.f, 0.f, 0.f, 0.f};
    __syncthreads();

#pragma unroll 4
    for (int ks = 0; ks < 16; ++ks) {
        int koff = (ks << 5) + ((lane >> 4) << 3);
        bf16x8 bq[4];
#pragma unroll
        for (int ct = 0; ct < 4; ++ct) {
            int brow = (wx << 6) + (ct << 4) + (lane & 15);
            int bb = (brow << 10) + (koff << 1); bb ^= (brow & 7) << 4;
            bq[ct] = *(const bf16x8*)(Bs + bb);
        }
#pragma unroll
        for (int rt = 0; rt < 4; ++rt) {
            bf16x8 aq = *(const bf16x8*)(aptr[rt] + koff);
#pragma unroll
            for (int ct = 0; ct < 4; ++ct)
                acc[rt][ct] = __builtin_amdgcn_mfma_f32_16x16x32_bf16(aq, bq[ct], acc[rt][ct], 0, 0, 0);
        }
    }
#pragma unroll
    for (int rt = 0; rt < 4; ++rt)
#pragma unroll
        for (int ct = 0; ct < 4; ++ct) {
            int n = n0 + (wx << 6) + (ct << 4) + (lane & 15);
            float badd = bias1[n] + bias2[n];
#pragma unroll
            for (int ri = 0; ri < 4; ++ri) {
                int m = m0 + (wy << 6) + (rt << 4) + ((lane >> 4) << 2) + ri;
                outf[(size_t)m * NG + n] = acc[rt][ct][ri] + badd;
            }
        }
}

// ---------- pipelined MFMA GEMM (gallc producer only) -------------------------
__launch_bounds__(256)
__global__ void pgemm10(const int* __restrict__ ridx,
                        const unsigned short* __restrict__ Aemb,
                        const unsigned short* __restrict__ Bbf,
                        const int* __restrict__ mact_p,
                        const float* __restrict__ gxf,
                        const int* __restrict__ rowlist,
                        unsigned short* __restrict__ outb) {
    __shared__ __align__(16) char lds[65536];   // A[2][16K] | B[2][16K]
    int Mact = *mact_p;
    int m0 = blockIdx.x * 128;
    if (m0 >= Mact) return;
    int n0 = blockIdx.y * 128;
    int tid = threadIdx.x;
    int lane = tid & 63, w = tid >> 6;
    int wy = w >> 1, wx = w & 1;
    int hi = lane >> 4, lo = lane & 15;

    const char* asrc[4];
#pragma unroll
    for (int i = 0; i < 4; ++i) {
        int p = (i << 8) + tid;
        int ma = m0 + (p >> 3); if (ma > Mact - 1) ma = Mact - 1;
        asrc[i] = (const char*)Aemb + ((size_t)ridx[ma] << 10);
    }

    auto stage = [&](int kt, int buf) {
#pragma unroll
        for (int i = 0; i < 4; ++i) {
            int p = (i << 8) + tid;
            int row = p >> 3, sc = (p & 7) ^ (row & 7);
            gl2lds16(asrc[i] + (kt << 7) + (sc << 4), lds + (buf << 14) + (p << 4));
        }
#pragma unroll
        for (int i = 0; i < 4; ++i) {
            int p = (i << 8) + tid;
            int row = p >> 3, sc = (p & 7) ^ (row & 7);
            int nb = n0 + row;
            gl2lds16((const char*)Bbf + ((size_t)nb << 10) + (kt << 7) + (sc << 4),
                     lds + 32768 + (buf << 14) + (p << 4));
        }
    };

    f32x4 acc[4][4];
#pragma unroll
    for (int i = 0; i < 4; ++i)
#pragma unroll
        for (int j = 0; j < 4; ++j) acc[i][j] = (f32x4){0.f, 0.f, 0.f, 0.f};

    stage(0, 0);
    __syncthreads();

    for (int kt = 0; kt < 8; ++kt) {
        int buf = kt & 1;
        if (kt < 7) stage(kt + 1, buf ^ 1);
#pragma unroll
        for (int kc = 0; kc < 2; ++kc) {
            bf16x8 aq[4], bq[4];
#pragma unroll
            for (int rt = 0; rt < 4; ++rt) {
                int ra = (wy << 6) + (rt << 4) + lo;
                int cha = ((kc << 2) + hi) ^ (ra & 7);
                aq[rt] = *(const bf16x8*)(lds + (buf << 14) + (ra << 7) + (cha << 4));
                int cb = (wx << 6) + (rt << 4) + lo;
                int chb = ((kc << 2) + hi) ^ (cb & 7);
                bq[rt] = *(const bf16x8*)(lds + 32768 + (buf << 14) + (cb << 7) + (chb << 4));
            }
#pragma unroll
            for (int rt = 0; rt < 4; ++rt)
#pragma unroll
                for (int ct = 0; ct < 4; ++ct)
                    acc[rt][ct] = __builtin_amdgcn_mfma_f32_16x16x32_bf16(aq[rt], bq[ct], acc[rt][ct], 0, 0, 0);
        }
        __syncthreads();
    }

#pragma unroll
    for (int rt = 0; rt < 4; ++rt)
#pragma unroll
        for (int ct = 0; ct < 4; ++ct) {
            int n = n0 + (wx << 6) + (ct << 4) + lo;
#pragma unroll
            for (int ri = 0; ri < 4; ++ri) {
                int m = m0 + (wy << 6) + (rt << 4) + (hi << 2) + ri;
                if (m < Mact) {
                    int b = rowlist[m] & 255;
                    float v = acc[rt][ct][ri] + gxf[(size_t)b * NG + n];
                    outb[(size_t)m * NG + ((n & 511) << 2) + (n >> 9)] = f2bf(v);
                }
            }
        }
}

// ---------- fused LSTM + output-GEMM work pool (cooperative) ------------------
// Phase 1 (t-loop): as round 11 — W-resident slices, single-writer flag sync,
// direct global->VGPR A loads. h_allc stores moved BEFORE flag post (consumed
// under flag ordering by phase 2).
// Phase 2 (workers): blocks that finished their t-loop grab output-GEMM tiles
// from a global queue, poll row-readiness via flags, and compute
// logitb = h_allc @ Wob^T + b_out (bf16) + rowsum exp-atomics.
__launch_bounds__(256, 1)
__global__ void lstmw_k(const unsigned short* __restrict__ Wimg2,  // [16][128KB]
                        const unsigned short* __restrict__ gallc,  // [n_active][512][4]
                        unsigned short* __restrict__ hx,           // [2][16][16KB image]
                        unsigned short* __restrict__ h_allc,      // [n_active][512]
                        int* __restrict__ flags,                   // [16][16] + [256]=queue
                        const int* __restrict__ cnt,
                        const int* __restrict__ start,
                        const unsigned short* __restrict__ Wob,    // [NV][512]
                        const float* __restrict__ bout,
                        unsigned short* __restrict__ logitb,       // [n_active][NV]
                        float* __restrict__ rowsum) {
    __shared__ __align__(16) char Wlds[131072];
    __shared__ float Gs[4 * 16 * 32];
    __shared__ __align__(16) unsigned short hstg[16 * 32];
    __shared__ int wq;
    int tid = threadIdx.x;
    int g = blockIdx.x & 15, s = blockIdx.x >> 4;
    int lane = tid & 63, w = tid >> 6;          // wave w = gate quarter q
    int hi = lane >> 4, lo = lane & 15;
    int q = w;

    // load W slice once (linear copy of pre-swizzled image)
    {
        const char* wsrc = (const char*)Wimg2 + ((size_t)s << 17) + tid * 16;
#pragma unroll 8
        for (int r = 0; r < 32; ++r)
            gl2lds16(wsrc + r * 4096, Wlds + tid * 16 + r * 4096);
    }
    asm volatile("s_waitcnt vmcnt(0)" ::: "memory");
    __syncthreads();

    int row = tid >> 4, d0 = tid & 15;          // elementwise ownership
    float creg[2] = {0.f, 0.f};

    // ---------------- phase 1: recurrence ----------------
    for (int t = 0; t < NT; ++t) {
        int cnt_t = cnt[t];
        if (16 * g >= cnt_t) break;
        int nrow = cnt_t - 16 * g; if (nrow > 16) nrow = 16;
        int pos0 = start[t] + 16 * g;

        int rr = row < nrow ? row : nrow - 1;
        const unsigned short* gp = gallc + ((size_t)(pos0 + rr) << 11);
        uint2 gq0 = *(const uint2*)(gp + (s * 32 + d0) * 4);
        uint2 gq1 = *(const uint2*)(gp + (s * 32 + d0 + 16) * 4);

        f32x4 acc[2];
        acc[0] = (f32x4){0.f, 0.f, 0.f, 0.f};
        acc[1] = (f32x4){0.f, 0.f, 0.f, 0.f};

        if (t > 0) {
            {
                const int* fp = flags + g * 16 + lo;
                int f;
                do {
                    asm volatile("global_load_dword %0, %1, off sc0 sc1\n\t"
                                 "s_waitcnt vmcnt(0)"
                                 : "=v"(f) : "v"(fp) : "memory");
                } while (__any(f < t));
            }
            const char* hb = (const char*)hx +
                ((size_t)(((t - 1) & 1) * 16 + g) << 14) + (lo << 6) + (hi << 4);
            uint4 hv[16];
#pragma unroll
            for (int c = 0; c < 16; ++c)
                asm volatile("global_load_dwordx4 %0, %1, off sc0 sc1"
                             : "=v"(hv[c]) : "v"(hb + (c << 10)) : "memory");
            asm volatile("s_waitcnt vmcnt(0)" ::: "memory");
            __builtin_amdgcn_sched_barrier(0);
#pragma unroll
            for (int kt = 0; kt < 16; ++kt) {
                bf16x8 aq = *(const bf16x8*)&hv[kt];
#pragma unroll
                for (int ct = 0; ct < 2; ++ct) {
                    int R = (q * 2 + ct) * 16 + lo;
                    int bb = (R << 10) + ((kt * 64 + hi * 16) ^ ((lo & 7) << 4));
                    bf16x8 bq = *(const bf16x8*)(Wlds + bb);
                    acc[ct] = __builtin_amdgcn_mfma_f32_16x16x32_bf16(aq, bq, acc[ct], 0, 0, 0);
                }
            }
        }
#pragma unroll
        for (int ct = 0; ct < 2; ++ct)
#pragma unroll
            for (int ri = 0; ri < 4; ++ri)
                Gs[(q * 16 + hi * 4 + ri) * 32 + ct * 16 + lo] = acc[ct][ri];
        __syncthreads();

        bool act = row < nrow;
#pragma unroll
        for (int pp = 0; pp < 2; ++pp) {
            int dp = d0 + pp * 16;
            const unsigned short* gq = (const unsigned short*)(pp ? &gq1 : &gq0);
            float iv = Gs[(0 * 16 + row) * 32 + dp] + bf2f(gq[0]);
            float fv = Gs[(1 * 16 + row) * 32 + dp] + bf2f(gq[1]);
            float gv = Gs[(2 * 16 + row) * 32 + dp] + bf2f(gq[2]);
            float ov = Gs[(3 * 16 + row) * 32 + dp] + bf2f(gq[3]);
            float i_ = 1.f / (1.f + __expf(-iv));
            float f_ = 1.f / (1.f + __expf(-fv));
            float o_ = 1.f / (1.f + __expf(-ov));
            float ea = __expf(-2.f * fabsf(gv));
            float th = (1.f - ea) / (1.f + ea);
            th = (gv < 0.f) ? -th : th;
            float cn = f_ * creg[pp] + i_ * th;
            float ec = __expf(-2.f * fabsf(cn));
            float tc = (1.f - ec) / (1.f + ec);
            tc = (cn < 0.f) ? -tc : tc;
            float hn = o_ * tc;
            unsigned short hv16;
            if (act) {
                creg[pp] = cn;
                hv16 = f2bf(hn);
            } else {
                hv16 = hstg[row * 32 + dp];   // forward h[t-1]
            }
            hstg[row * 32 + dp] = hv16;
        }
        __syncthreads();

        // image + h_allc stores (both before flag post; h_allc consumed by workers)
        int crow = tid >> 2, j = tid & 3;
        if (tid < 64) {
            uint2 v0 = *(const uint2*)(hstg + crow * 32 + j * 8);
            uint2 v1 = *(const uint2*)(hstg + crow * 32 + j * 8 + 4);
            char* himg = (char*)hx + ((size_t)((t & 1) * 16 + g) << 14);
            int dstoff = (s << 10) + (crow << 6) + (j << 4);
            asm volatile("global_store_dwordx2 %0, %2, off sc0 sc1\n\t"
                         "global_store_dwordx2 %1, %3, off sc0 sc1"
                         :: "v"(himg + dstoff), "v"(himg + dstoff + 8),
                            "v"(v0), "v"(v1) : "memory");
            if (crow < nrow) {
                unsigned short* hap = h_allc + (size_t)(pos0 + crow) * NH + s * 32 + j * 8;
                asm volatile("global_store_dwordx2 %0, %2, off sc0 sc1\n\t"
                             "global_store_dwordx2 %1, %3, off sc0 sc1"
                             :: "v"(hap), "v"(hap + 4), "v"(v0), "v"(v1) : "memory");
            }
        }
        asm volatile("s_waitcnt vmcnt(0)" ::: "memory");
        __syncthreads();   // all stores drained before post
        if (tid == 0) {
            int fv = t + 1;
            asm volatile("global_store_dword %0, %1, off sc0 sc1"
                         :: "v"(flags + g * 16 + s), "v"(fv) : "memory");
        }
    }

    // ---------------- phase 2: output-GEMM work pool ----------------
    {
        char* glds = Wlds;                 // alias: A[2][16K] | B[2][16K]
        int Mact = start[NT];
        int mtiles = (Mact + 127) >> 7;
        int total = mtiles * NTILES_N;
        int wyW = w >> 1, wxW = w & 1;

        for (;;) {
            if (tid == 0) wq = atomicAdd(flags + 256, 1);
            __syncthreads();
            int idx = wq;
            if (idx >= total) break;
            int tm = idx / NTILES_N;
            int tn = idx - tm * NTILES_N;
            int m0w = tm << 7, n0w = tn << 7;
            int mEnd = m0w + 128; if (mEnd > Mact) mEnd = Mact;

            // readiness: rows [m0w, mEnd) written => flags[g*16+s] >= t+1
            if (tid < 16) {
                bool ok;
                do {
                    ok = true;
                    for (int t = 0; t < NT && ok; ++t) {
                        int st = start[t], cn = cnt[t];
                        int lo2 = st > m0w ? st : m0w;
                        int hi2 = (st + cn < mEnd) ? (st + cn) : mEnd;
                        if (lo2 < hi2) {
                            int glo = (lo2 - st) >> 4, ghi = (hi2 - 1 - st) >> 4;
                            for (int gg = glo; gg <= ghi; ++gg) {
                                int f;
                                asm volatile("global_load_dword %0, %1, off sc0 sc1\n\t"
                                             "s_waitcnt vmcnt(0)"
                                             : "=v"(f) : "v"(flags + gg * 16 + tid) : "memory");
                                if (f < t + 1) { ok = false; break; }
                            }
                        }
                    }
                    if (!ok) __builtin_amdgcn_s_sleep(8);
                } while (!ok);
            }
            __syncthreads();

            f32x4 acc[4][4];
#pragma unroll
            for (int i = 0; i < 4; ++i)
#pragma unroll
                for (int jj = 0; jj < 4; ++jj) acc[i][jj] = (f32x4){0.f, 0.f, 0.f, 0.f};

            uint4 areg[4];
            auto issueA = [&](int kt) {
#pragma unroll
                for (int i = 0; i < 4; ++i) {
                    int p = (i << 8) + tid;
                    int rw = p >> 3, sc = (p & 7) ^ (rw & 7);
                    int ma = m0w + rw; if (ma > Mact - 1) ma = Mact - 1;
                    asm volatile("global_load_dwordx4 %0, %1, off sc0 sc1"
                                 : "=v"(areg[i])
                                 : "v"((const char*)h_allc + ((size_t)ma << 10) + (kt << 7) + (sc << 4))
                                 : "memory");
                }
            };
            auto issueB = [&](int kt, int buf) {
#pragma unroll
                for (int i = 0; i < 4; ++i) {
                    int p = (i << 8) + tid;
                    int rw = p >> 3, sc = (p & 7) ^ (rw & 7);
                    int nb = n0w + rw; if (nb > NV - 1) nb = NV - 1;
                    gl2lds16((const char*)Wob + ((size_t)nb << 10) + (kt << 7) + (sc << 4),
                             glds + 32768 + (buf << 14) + (p << 4));
                }
            };
            auto writeA = [&](int buf) {
#pragma unroll
                for (int i = 0; i < 4; ++i) {
                    int p = (i << 8) + tid;
                    *(uint4*)(glds + (buf << 14) + (p << 4)) = areg[i];
                }
            };

            issueA(0); issueB(0, 0);
            asm volatile("s_waitcnt vmcnt(0)" ::: "memory");
            writeA(0);
            __syncthreads();

            for (int kt = 0; kt < 8; ++kt) {
                int buf = kt & 1;
                if (kt < 7) { issueA(kt + 1); issueB(kt + 1, buf ^ 1); }
#pragma unroll
                for (int kc = 0; kc < 2; ++kc) {
                    bf16x8 aq[4], bq[4];
#pragma unroll
                    for (int rt = 0; rt < 4; ++rt) {
                        int ra = (wyW << 6) + (rt << 4) + lo;
                        int cha = ((kc << 2) + hi) ^ (ra & 7);
                        aq[rt] = *(const bf16x8*)(glds + (buf << 14) + (ra << 7) + (cha << 4));
                        int cb = (wxW << 6) + (rt << 4) + lo;
                        int chb = ((kc << 2) + hi) ^ (cb & 7);
                        bq[rt] = *(const bf16x8*)(glds + 32768 + (buf << 14) + (cb << 7) + (chb << 4));
                    }
#pragma unroll
                    for (int rt = 0; rt < 4; ++rt)
#pragma unroll
                        for (int ct = 0; ct < 4; ++ct)
                            acc[rt][ct] = __builtin_amdgcn_mfma_f32_16x16x32_bf16(aq[rt], bq[ct], acc[rt][ct], 0, 0, 0);
                }
                if (kt < 7) {
                    asm volatile("s_waitcnt vmcnt(0)" ::: "memory");
                    writeA(buf ^ 1);
                }
                __syncthreads();
            }

            // epilogue: bf16 logits + per-row sum(exp) atomics
#pragma unroll
            for (int rt = 0; rt < 4; ++rt) {
                float es4[4] = {0.f, 0.f, 0.f, 0.f};
#pragma unroll
                for (int ct = 0; ct < 4; ++ct) {
                    int n = n0w + (wxW << 6) + (ct << 4) + lo;
                    bool okn = (n < NV);
                    float bo = okn ? bout[n] : 0.f;
#pragma unroll
                    for (int ri = 0; ri < 4; ++ri) {
                        int m = m0w + (wyW << 6) + (rt << 4) + (hi << 2) + ri;
                        float v = acc[rt][ct][ri] + bo;
                        if (okn && m < Mact) {
                            logitb[(size_t)m * NV + n] = f2bf(v);
                            es4[ri] += __expf(v);
                        }
                    }
                }
#pragma unroll
                for (int ri = 0; ri < 4; ++ri) {
                    float ssum = es4[ri];
                    ssum += __shfl_xor(ssum, 1); ssum += __shfl_xor(ssum, 2);
                    ssum += __shfl_xor(ssum, 4); ssum += __shfl_xor(ssum, 8);
                    if (lo == 0) {
                        int m = m0w + (wyW << 6) + (rt << 4) + (hi << 2) + ri;
                        if (m < Mact) atomicAdd(&rowsum[m], ssum);
                    }
                }
            }
            __syncthreads();
        }
    }
}

// ---------- final pass: preds = bf2f(logit) - log(rowsum); zeros elsewhere ----
__global__ void norm_k(float* __restrict__ out, const unsigned short* __restrict__ logitb,
                       const float* __restrict__ rowsum,
                       const int* __restrict__ cnt, const int* __restrict__ start) {
    int r = blockIdx.x;          // r = t*256+b, t in [0,31)
    int t = r >> 8, b = r & 255;
    bool act = (t < NT) && (b < cnt[t]);
    float4* row = (float4*)(out + (size_t)b * PRED_B + (size_t)t * NV);
    int tid = threadIdx.x;
    if (act) {
        int pos = start[t] + b;
        float lse = logf(rowsum[pos]);
        const uint4* lrow = (const uint4*)(logitb + (size_t)pos * NV);
        for (int v8 = tid; v8 < NV / 8; v8 += 256) {
            uint4 u = lrow[v8];
            float4 a, c;
            a.x = bf2f((unsigned short)u.x) - lse;
            a.y = bf2f((unsigned short)(u.x >> 16)) - lse;
            a.z = bf2f((unsigned short)u.y) - lse;
            a.w = bf2f((unsigned short)(u.y >> 16)) - lse;
            c.x = bf2f((unsigned short)u.z) - lse;
            c.y = bf2f((unsigned short)(u.z >> 16)) - lse;
            c.z = bf2f((unsigned short)u.w) - lse;
            c.w = bf2f((unsigned short)(u.w >> 16)) - lse;
            row[v8 * 2] = a;
            row[v8 * 2 + 1] = c;
        }
    } else {
        float4 z = make_float4(0.f, 0.f, 0.f, 0.f);
        for (int v4 = tid; v4 < NV / 4; v4 += 256) row[v4] = z;
    }
}

extern "C" void kernel_launch(void* const* d_in, const int* in_sizes, int n_in,
                              void* d_out, int out_size, void* d_ws, size_t ws_size,
                              hipStream_t stream) {
    const float* gimg  = (const float*)d_in[0];
    const int*   w_in  = (const int*)d_in[1];
    const int*   lens  = (const int*)d_in[2];
    const float* emb   = (const float*)d_in[3];
    const float* W_ih  = (const float*)d_in[4];
    const float* W_hh  = (const float*)d_in[5];
    const float* b_ih  = (const float*)d_in[6];
    const float* b_hh  = (const float*)d_in[7];
    const float* W_out = (const float*)d_in[8];
    const float* b_out = (const float*)d_in[9];
    float* out = (float*)d_out;

    char* p = (char*)d_ws;
    auto alloc = [&](size_t bytes) -> char* {
        char* r = p;
        p += (bytes + 255) & ~(size_t)255;
        return r;
    };
    int*   order   = (int*)alloc(NB * 4);
    int*   wsort   = (int*)alloc(NB * ML * 4);
    int*   cnt     = (int*)alloc(NT * 4);
    int*   start   = (int*)alloc((NT + 1) * 4);
    int*   flags   = (int*)alloc(512 * 4);          // [0..255] flags, [256] tile queue
    int*   rowlist = (int*)alloc((size_t)NT * NB * 4);
    int*   rowwc   = (int*)alloc((size_t)NT * NB * 4);
    float* gx      = (float*)alloc((size_t)NB * NG * 4);
    float* rowsum  = (float*)alloc((size_t)NT * NB * 4);
    unsigned short* g_sb   = (unsigned short*)alloc((size_t)NB * NE * 2);
    unsigned short* hx     = (unsigned short*)alloc((size_t)2 * 16 * 16384);
    unsigned short* h_allc = (unsigned short*)alloc((size_t)NT * NB * NH * 2);
    unsigned short* Wimg2  = (unsigned short*)alloc((size_t)NG * NH * 2);
    unsigned short* Wxl    = (unsigned short*)alloc((size_t)NG * NE * 2);
    unsigned short* Wxb    = (unsigned short*)alloc((size_t)NG * NE * 2);
    unsigned short* Wob    = (unsigned short*)alloc((size_t)NV * NH * 2);
    unsigned short* embb   = (unsigned short*)alloc((size_t)NV * NE * 2);
    unsigned short* gallc  = (unsigned short*)alloc((size_t)NT * NB * NG * 2);
    unsigned short* logitb = (unsigned short*)alloc((size_t)NT * NB * NV * 2);
    int* nact = start + NT;   // n_active lives at start[30]

    sort_k<<<1, 256, 0, stream>>>(lens, order, cnt, start, flags, out + OFF_DEC);
    gather_k<<<NB, 256, 0, stream>>>(gimg, w_in, order, g_sb, wsort, out + OFF_TGT);
    rowlist_k<<<NT, 256, 0, stream>>>(wsort, cnt, start, rowlist, rowwc, rowsum);
    prep_k<<<12560, 256, 0, stream>>>(W_ih, W_hh, W_out, emb, Wxl, Wxb, Wob, embb, Wimg2);

    // gx = g_sb @ Wxl^T + b_ih + b_hh     (256 x 2048, K=512, fp32 out)
    gxgemm<<<dim3(NG / 128, NB / 128), 256, 0, stream>>>(g_sb, Wxl, b_ih, b_hh, gx);

    // gallc[pos][d][q] = bf16( emb[rowwc[pos]] @ Wxb^T + gx[b] )   (n_active x 2048)
    pgemm10<<<dim3(NT * NB / 128, NG / 128), 256, 0, stream>>>(
        rowwc, embb, Wxb, nact, gx, rowlist, gallc);

    // fused recurrence + overlapped output GEMM (cooperative)
    {
        void* cargs[] = { (void*)&Wimg2, (void*)&gallc, (void*)&hx, (void*)&h_allc,
                          (void*)&flags, (void*)&cnt, (void*)&start,
                          (void*)&Wob, (void*)&b_out, (void*)&logitb, (void*)&rowsum };
        (void)hipLaunchCooperativeKernel((void*)lstmw_k, dim3(256), dim3(256), cargs, 0, stream);
    }

    norm_k<<<(NT + 1) * NB, 256, 0, stream>>>(out, logitb, rowsum, cnt, start);
}

// Round 13
// 423.277 us; speedup vs baseline: 1.2411x; 1.2411x over previous
//
#include <hip/hip_runtime.h>
#include <hip/hip_bf16.h>
#include <math.h>

// Problem constants
#define NB   256      // batch
#define ML   31       // MAX_LEN
#define NT   30       // T = MAX_LEN-1 decode steps
#define NV   10000    // vocab
#define NH   512      // hidden
#define NE   512      // embed
#define NG   2048     // 4*H gates

// Output layout (floats): preds (256,31,10000) | target (256,30) | dec_len (256,)
#define OFF_TGT  (256LL*31LL*10000LL)
#define OFF_DEC  (OFF_TGT + 256LL*30LL)
#define PRED_B   (31LL*10000LL)

typedef __attribute__((ext_vector_type(8))) short bf16x8;
typedef __attribute__((ext_vector_type(4))) float f32x4;

__device__ inline unsigned short f2bf(float f) {
    unsigned int x = __float_as_uint(f);
    unsigned int r = x + 0x7FFFu + ((x >> 16) & 1u);   // RNE
    return (unsigned short)(r >> 16);
}
__device__ inline float bf2f(unsigned short u) {
    return __uint_as_float((unsigned int)u << 16);
}

__device__ inline void gl2lds16(const void* g, void* l) {
    __builtin_amdgcn_global_load_lds(
        (const __attribute__((address_space(1))) unsigned int*)g,
        (__attribute__((address_space(3))) unsigned int*)l, 16, 0, 0);
}

// ---------- sort: stable descending argsort + counts + zero flags -------------
__global__ void sort_k(const int* __restrict__ lens, int* __restrict__ order,
                       int* __restrict__ cnt, int* __restrict__ start,
                       int* __restrict__ flags, float* __restrict__ out_dec) {
    __shared__ int sd[NB];
    int i = threadIdx.x;
    flags[i] = 0;
    int li = lens[i];
    int r = 0;
    for (int j = 0; j < NB; j++) {
        int lj = lens[j];
        r += (lj > li) || (lj == li && j < i);
    }
    order[r] = i;
    out_dec[r] = (float)(li - 1);
    sd[r] = li - 1;
    __syncthreads();
    if (i < NT) {
        int c = 0;
        for (int b = 0; b < NB; b++) c += (sd[b] > i);
        cnt[i] = c;
    }
    __syncthreads();
    if (i == 0) {
        int s = 0;
        for (int t = 0; t < NT; t++) { start[t] = s; s += cnt[t]; }
        start[NT] = s;                 // n_active
    }
}

// ---------- gather sorted rows + compact active-row lists + zero rowsum -------
// block r: gather row r (bf16 image, wsort, target). For r < NT it also plays
// the old rowlist_k role for timestep t=r (rowwc from w_in[order[b]] directly,
// so no dependency on other blocks' wsort writes).
__global__ void gather_k(const float* __restrict__ gimg, const int* __restrict__ w_in,
                         const int* __restrict__ order,
                         const int* __restrict__ cnt, const int* __restrict__ start,
                         unsigned short* __restrict__ g_sb, int* __restrict__ wsort,
                         int* __restrict__ rowlist, int* __restrict__ rowwc,
                         float* __restrict__ rowsum,
                         float* __restrict__ out_tgt) {
    int r = blockIdx.x, tid = threadIdx.x;
    int o = order[r];
    for (int e = tid; e < NE; e += 256)
        g_sb[r * NE + e] = f2bf(gimg[o * NE + e]);
    if (tid < ML) wsort[r * ML + tid] = w_in[o * ML + tid];
    if (tid < NT) out_tgt[r * NT + tid] = (float)w_in[o * ML + tid + 1];
    if (r < NT) {
        rowsum[r * 256 + tid] = 0.f;
        if (tid < cnt[r]) {
            int pos = start[r] + tid;
            rowlist[pos] = r * 256 + tid;
            rowwc[pos] = w_in[order[tid] * ML + r];
        }
    }
}

// ---------- fused preamble conversions ----------------------------------------
__global__ void prep_k(const float* __restrict__ W_ih, const float* __restrict__ W_hh,
                       const float* __restrict__ W_out, const float* __restrict__ emb,
                       unsigned short* __restrict__ Wxl, unsigned short* __restrict__ Wxb,
                       unsigned short* __restrict__ Wob, unsigned short* __restrict__ embb,
                       unsigned short* __restrict__ Wimg2) {
    int bid = blockIdx.x, tid = threadIdx.x;
    if (bid < 2048) {
        int koff = (bid < 1024) ? 0 : NE;
        unsigned short* dst = (bid < 1024) ? Wxl : Wxb;
        int gid = ((bid & 1023) << 8) + tid;        // 2048*128 float4 chunks
        int j = gid >> 7, k4 = gid & 127;
        float4 v = *(const float4*)(W_ih + (size_t)j * (2 * NE) + koff + k4 * 4);
        ushort4 o;
        o.x = f2bf(v.x); o.y = f2bf(v.y); o.z = f2bf(v.z); o.w = f2bf(v.w);
        *(ushort4*)(dst + (size_t)j * NE + k4 * 4) = o;
    } else if (bid < 12048) {
        const float* src = (bid < 7048) ? W_out : emb;
        unsigned short* dst = (bid < 7048) ? Wob : embb;
        int gid = ((bid < 7048 ? bid - 2048 : bid - 7048) << 8) + tid;
        float4 v = ((const float4*)src)[gid];
        ushort4 o;
        o.x = f2bf(v.x); o.y = f2bf(v.y); o.z = f2bf(v.z); o.w = f2bf(v.w);
        ((ushort4*)dst)[gid] = o;
    } else {
        int gid = ((bid - 12048) << 8) + tid;       // 131072 = 16s*128R*16kt*4hi
        int hi = gid & 3, kt = (gid >> 2) & 15, R = (gid >> 6) & 127, s = gid >> 13;
        int q = R >> 5, ct = (R >> 4) & 1, lo = R & 15;
        int col = q * 512 + s * 32 + ct * 16 + lo;
        int k = kt * 32 + hi * 8;
        const float* src = W_hh + (size_t)col * NH + k;
        __align__(16) unsigned short o[8];
#pragma unroll
        for (int j = 0; j < 8; ++j) o[j] = f2bf(src[j]);
        int ba = (R << 10) + ((kt * 64 + hi * 16) ^ ((lo & 7) << 4));
        *(uint4*)((char*)Wimg2 + ((size_t)s << 17) + ba) = *(const uint4*)o;
    }
}

// ---------- small fp32-out GEMM for gx (B-panel-once, A direct) ---------------
__launch_bounds__(256)
__global__ void gxgemm(const unsigned short* __restrict__ Abf,
                       const unsigned short* __restrict__ Bbf,
                       const float* __restrict__ bias1, const float* __restrict__ bias2,
                       float* __restrict__ outf) {
    __shared__ __align__(16) char Bs[131072];   // [128][512] bf16, XOR-swizzled
    int m0 = blockIdx.y * 128, n0 = blockIdx.x * 128;
    int tid = threadIdx.x;
    int lane = tid & 63, w = tid >> 6;
    int wy = w >> 1, wx = w & 1;

#pragma unroll 4
    for (int p = 0; p < 32; ++p) {
        int row = (tid >> 6) + (p << 2);
        uint4 v = *(const uint4*)(Bbf + ((size_t)(n0 + row) << 9) + ((tid & 63) << 3));
        int ba = (row << 10) + ((tid & 63) << 4); ba ^= (row & 7) << 4;
        *(uint4*)(Bs + ba) = v;
    }
    const unsigned short* aptr[4];
#pragma unroll
    for (int rt = 0; rt < 4; ++rt)
        aptr[rt] = Abf + ((size_t)(m0 + (wy << 6) + (rt << 4) + (lane & 15)) << 9);

    f32x4 acc[4][4];
#pragma unroll
    for (int i = 0; i < 4; ++i)
#pragma unroll
        for (int j = 0; j < 4; ++j) acc[i][j] = (f32x4){0.f, 0.f, 0.f, 0.f};
    __syncthreads();

#pragma unroll 4
    for (int ks = 0; ks < 16; ++ks) {
        int koff = (ks << 5) + ((lane >> 4) << 3);
        bf16x8 bq[4];
#pragma unroll
        for (int ct = 0; ct < 4; ++ct) {
            int brow = (wx << 6) + (ct << 4) + (lane & 15);
            int bb = (brow << 10) + (koff << 1); bb ^= (brow & 7) << 4;
            bq[ct] = *(const bf16x8*)(Bs + bb);
        }
#pragma unroll
        for (int rt = 0; rt < 4; ++rt) {
            bf16x8 aq = *(const bf16x8*)(aptr[rt] + koff);
#pragma unroll
            for (int ct = 0; ct < 4; ++ct)
                acc[rt][ct] = __builtin_amdgcn_mfma_f32_16x16x32_bf16(aq, bq[ct], acc[rt][ct], 0, 0, 0);
        }
    }
#pragma unroll
    for (int rt = 0; rt < 4; ++rt)
#pragma unroll
        for (int ct = 0; ct < 4; ++ct) {
            int n = n0 + (wx << 6) + (ct << 4) + (lane & 15);
            float badd = bias1[n] + bias2[n];
#pragma unroll
            for (int ri = 0; ri < 4; ++ri) {
                int m = m0 + (wy << 6) + (rt << 4) + ((lane >> 4) << 2) + ri;
                outf[(size_t)m * NG + n] = acc[rt][ct][ri] + badd;
            }
        }
}

// ---------- pipelined MFMA GEMM (m97-style, global_load_lds dbuf) -------------
// Grid: x = m-tile, y = n-tile.
// EPI 0: gallc permuted write + gx fold
// EPI 1: bf16 logits to outb[m*NV+n] + rowsum exp-atomics
template <int AMODE, int EPI>
__launch_bounds__(256)
__global__ void pgemm(const unsigned short* __restrict__ Abf,
                      const int* __restrict__ ridx,
                      const unsigned short* __restrict__ Aemb,
                      const unsigned short* __restrict__ Bbf,
                      int N,
                      const int* __restrict__ mact_p,
                      const float* __restrict__ bias1,   // EPI1: b_out; EPI0: gx[256][2048]
                      const int* __restrict__ rowlist,
                      unsigned short* __restrict__ outb,
                      float* __restrict__ rowsum) {
    __shared__ __align__(16) char lds[65536];   // A[2][16K] | B[2][16K]
    int Mact = *mact_p;
    int m0 = blockIdx.x * 128;
    if (m0 >= Mact) return;
    int n0 = blockIdx.y * 128;
    int tid = threadIdx.x;
    int lane = tid & 63, w = tid >> 6;
    int wy = w >> 1, wx = w & 1;
    int hi = lane >> 4, lo = lane & 15;

    const char* asrc[4];
#pragma unroll
    for (int i = 0; i < 4; ++i) {
        int p = (i << 8) + tid;
        int ma = m0 + (p >> 3); if (ma > Mact - 1) ma = Mact - 1;
        if (AMODE == 0) asrc[i] = (const char*)Abf + ((size_t)ma << 10);
        else            asrc[i] = (const char*)Aemb + ((size_t)ridx[ma] << 10);
    }

    auto stage = [&](int kt, int buf) {
#pragma unroll
        for (int i = 0; i < 4; ++i) {
            int p = (i << 8) + tid;
            int row = p >> 3, sc = (p & 7) ^ (row & 7);
            gl2lds16(asrc[i] + (kt << 7) + (sc << 4), lds + (buf << 14) + (p << 4));
        }
#pragma unroll
        for (int i = 0; i < 4; ++i) {
            int p = (i << 8) + tid;
            int row = p >> 3, sc = (p & 7) ^ (row & 7);
            int nb = n0 + row; if (nb > N - 1) nb = N - 1;
            gl2lds16((const char*)Bbf + ((size_t)nb << 10) + (kt << 7) + (sc << 4),
                     lds + 32768 + (buf << 14) + (p << 4));
        }
    };

    f32x4 acc[4][4];
#pragma unroll
    for (int i = 0; i < 4; ++i)
#pragma unroll
        for (int j = 0; j < 4; ++j) acc[i][j] = (f32x4){0.f, 0.f, 0.f, 0.f};

    stage(0, 0);
    __syncthreads();

    for (int kt = 0; kt < 8; ++kt) {
        int buf = kt & 1;
        if (kt < 7) stage(kt + 1, buf ^ 1);
#pragma unroll
        for (int kc = 0; kc < 2; ++kc) {
            bf16x8 aq[4], bq[4];
#pragma unroll
            for (int rt = 0; rt < 4; ++rt) {
                int ra = (wy << 6) + (rt << 4) + lo;
                int cha = ((kc << 2) + hi) ^ (ra & 7);
                aq[rt] = *(const bf16x8*)(lds + (buf << 14) + (ra << 7) + (cha << 4));
                int cb = (wx << 6) + (rt << 4) + lo;
                int chb = ((kc << 2) + hi) ^ (cb & 7);
                bq[rt] = *(const bf16x8*)(lds + 32768 + (buf << 14) + (cb << 7) + (chb << 4));
            }
#pragma unroll
            for (int rt = 0; rt < 4; ++rt)
#pragma unroll
                for (int ct = 0; ct < 4; ++ct)
                    acc[rt][ct] = __builtin_amdgcn_mfma_f32_16x16x32_bf16(aq[rt], bq[ct], acc[rt][ct], 0, 0, 0);
        }
        __syncthreads();
    }

    if (EPI == 0) {
#pragma unroll
        for (int rt = 0; rt < 4; ++rt)
#pragma unroll
            for (int ct = 0; ct < 4; ++ct) {
                int n = n0 + (wx << 6) + (ct << 4) + lo;
#pragma unroll
                for (int ri = 0; ri < 4; ++ri) {
                    int m = m0 + (wy << 6) + (rt << 4) + (hi << 2) + ri;
                    if (m < Mact) {
                        int b = rowlist[m] & 255;
                        float v = acc[rt][ct][ri] + bias1[(size_t)b * NG + n];
                        outb[(size_t)m * NG + ((n & 511) << 2) + (n >> 9)] = f2bf(v);
                    }
                }
            }
    } else {
#pragma unroll
        for (int rt = 0; rt < 4; ++rt) {
            float es4[4] = {0.f, 0.f, 0.f, 0.f};
#pragma unroll
            for (int ct = 0; ct < 4; ++ct) {
                int n = n0 + (wx << 6) + (ct << 4) + lo;
                bool okn = (n < N);
                float bo = okn ? bias1[n] : 0.f;
#pragma unroll
                for (int ri = 0; ri < 4; ++ri) {
                    int m = m0 + (wy << 6) + (rt << 4) + (hi << 2) + ri;
                    float v = acc[rt][ct][ri] + bo;
                    if (okn && m < Mact) {
                        outb[(size_t)m * NV + n] = f2bf(v);
                        es4[ri] += __expf(v);
                    }
                }
            }
#pragma unroll
            for (int ri = 0; ri < 4; ++ri) {
                float s = es4[ri];
                s += __shfl_xor(s, 1); s += __shfl_xor(s, 2);
                s += __shfl_xor(s, 4); s += __shfl_xor(s, 8);
                if (lo == 0) {
                    int m = m0 + (wy << 6) + (rt << 4) + (hi << 2) + ri;
                    if (m < Mact) atomicAdd(&rowsum[m], s);
                }
            }
        }
    }
}

// ---------- fused LSTM: W-resident, slice-contiguous image, direct A loads ----
__launch_bounds__(256, 1)
__global__ void lstmy_k(const unsigned short* __restrict__ Wimg2,  // [16][128KB]
                        const unsigned short* __restrict__ gallc,  // [n_active][512][4]
                        unsigned short* __restrict__ hx,           // [2][16][16KB image]
                        unsigned short* __restrict__ h_allc,       // [n_active][512]
                        int* __restrict__ flags,                   // [16][16]
                        const int* __restrict__ cnt,
                        const int* __restrict__ start) {
    __shared__ __align__(16) char Wlds[131072];
    __shared__ float Gs[4 * 16 * 32];
    __shared__ __align__(16) unsigned short hstg[16 * 32];   // this block's slice
    int tid = threadIdx.x;
    int g = blockIdx.x & 15, s = blockIdx.x >> 4;
    int lane = tid & 63, w = tid >> 6;          // wave w = gate quarter q
    int hi = lane >> 4, lo = lane & 15;
    int q = w;

    // load W slice once (linear copy of pre-swizzled image)
    {
        const char* wsrc = (const char*)Wimg2 + ((size_t)s << 17) + tid * 16;
#pragma unroll 8
        for (int r = 0; r < 32; ++r)
            gl2lds16(wsrc + r * 4096, Wlds + tid * 16 + r * 4096);
    }
    asm volatile("s_waitcnt vmcnt(0)" ::: "memory");
    __syncthreads();

    int row = tid >> 4, d0 = tid & 15;          // elementwise ownership
    float creg[2] = {0.f, 0.f};

    for (int t = 0; t < NT; ++t) {
        int cnt_t = cnt[t];
        if (16 * g >= cnt_t) break;
        int nrow = cnt_t - 16 * g; if (nrow > 16) nrow = 16;
        int pos0 = start[t] + 16 * g;

        // issue x-preact loads early (stable data, plain cached loads)
        int rr = row < nrow ? row : nrow - 1;
        const unsigned short* gp = gallc + ((size_t)(pos0 + rr) << 11);
        uint2 gq0 = *(const uint2*)(gp + (s * 32 + d0) * 4);
        uint2 gq1 = *(const uint2*)(gp + (s * 32 + d0 + 16) * 4);

        f32x4 acc[2];
        acc[0] = (f32x4){0.f, 0.f, 0.f, 0.f};
        acc[1] = (f32x4){0.f, 0.f, 0.f, 0.f};

        if (t > 0) {
            // wave-level poll: all 16 producers of group g posted step t-1
            {
                const int* fp = flags + g * 16 + lo;
                int f;
                do {
                    asm volatile("global_load_dword %0, %1, off sc0 sc1\n\t"
                                 "s_waitcnt vmcnt(0)"
                                 : "=v"(f) : "v"(fp) : "memory");
                } while (__any(f < t));
            }
            // direct global->VGPR A-frag loads: 16 slices x 16B/lane, parallel
            const char* hb = (const char*)hx +
                ((size_t)(((t - 1) & 1) * 16 + g) << 14) + (lo << 6) + (hi << 4);
            uint4 hv[16];
#pragma unroll
            for (int c = 0; c < 16; ++c)
                asm volatile("global_load_dwordx4 %0, %1, off sc0 sc1"
                             : "=v"(hv[c]) : "v"(hb + (c << 10)) : "memory");
            asm volatile("s_waitcnt vmcnt(0)" ::: "memory");
            __builtin_amdgcn_sched_barrier(0);
#pragma unroll
            for (int kt = 0; kt < 16; ++kt) {
                bf16x8 aq = *(const bf16x8*)&hv[kt];
#pragma unroll
                for (int ct = 0; ct < 2; ++ct) {
                    int R = (q * 2 + ct) * 16 + lo;
                    int bb = (R << 10) + ((kt * 64 + hi * 16) ^ ((lo & 7) << 4));
                    bf16x8 bq = *(const bf16x8*)(Wlds + bb);
                    acc[ct] = __builtin_amdgcn_mfma_f32_16x16x32_bf16(aq, bq, acc[ct], 0, 0, 0);
                }
            }
        }
        // gate exchange: Gs[q][row][d']
#pragma unroll
        for (int ct = 0; ct < 2; ++ct)
#pragma unroll
            for (int ri = 0; ri < 4; ++ri)
                Gs[(q * 16 + hi * 4 + ri) * 32 + ct * 16 + lo] = acc[ct][ri];
        __syncthreads();

        // elementwise: this thread owns (row, d0) and (row, d0+16)
        bool act = row < nrow;
#pragma unroll
        for (int p = 0; p < 2; ++p) {
            int dp = d0 + p * 16;
            const unsigned short* gq = (const unsigned short*)(p ? &gq1 : &gq0);
            float iv = Gs[(0 * 16 + row) * 32 + dp] + bf2f(gq[0]);
            float fv = Gs[(1 * 16 + row) * 32 + dp] + bf2f(gq[1]);
            float gv = Gs[(2 * 16 + row) * 32 + dp] + bf2f(gq[2]);
            float ov = Gs[(3 * 16 + row) * 32 + dp] + bf2f(gq[3]);
            float i_ = 1.f / (1.f + __expf(-iv));
            float f_ = 1.f / (1.f + __expf(-fv));
            float o_ = 1.f / (1.f + __expf(-ov));
            float ea = __expf(-2.f * fabsf(gv));
            float th = (1.f - ea) / (1.f + ea);
            th = (gv < 0.f) ? -th : th;
            float cn = f_ * creg[p] + i_ * th;
            float ec = __expf(-2.f * fabsf(cn));
            float tc = (1.f - ec) / (1.f + ec);
            tc = (cn < 0.f) ? -tc : tc;
            float hn = o_ * tc;
            unsigned short hv16;
            if (act) {
                creg[p] = cn;
                hv16 = f2bf(hn);
            } else {
                hv16 = hstg[row * 32 + dp];   // forward h[t-1] (kept from prev step)
            }
            hstg[row * 32 + dp] = hv16;
        }
        __syncthreads();

        // slice-contiguous image store (critical path) -> flag -> h_allc
        uint2 v0, v1;
        int crow = tid >> 2, j = tid & 3;
        if (tid < 64) {
            v0 = *(const uint2*)(hstg + crow * 32 + j * 8);
            v1 = *(const uint2*)(hstg + crow * 32 + j * 8 + 4);
            char* himg = (char*)hx + ((size_t)((t & 1) * 16 + g) << 14);
            int dstoff = (s << 10) + (crow << 6) + (j << 4);
            asm volatile("global_store_dwordx2 %0, %2, off sc0 sc1\n\t"
                         "global_store_dwordx2 %1, %3, off sc0 sc1"
                         :: "v"(himg + dstoff), "v"(himg + dstoff + 8),
                            "v"(v0), "v"(v1) : "memory");
        }
        asm volatile("s_waitcnt vmcnt(0)" ::: "memory");
        __syncthreads();   // image stores drained before post
        if (tid == 0) {
            int fv = t + 1;
            asm volatile("global_store_dword %0, %1, off sc0 sc1"
                         :: "v"(flags + g * 16 + s), "v"(fv) : "memory");
        }
        if (tid < 64 && crow < nrow) {
            unsigned short* hap = h_allc + (size_t)(pos0 + crow) * NH + s * 32 + j * 8;
            *(uint2*)hap = v0;
            *(uint2*)(hap + 4) = v1;
        }
    }
}

// ---------- final pass: preds = bf2f(logit) - log(rowsum); zeros elsewhere ----
__global__ void norm_k(float* __restrict__ out, const unsigned short* __restrict__ logitb,
                       const float* __restrict__ rowsum,
                       const int* __restrict__ cnt, const int* __restrict__ start) {
    int r = blockIdx.x;          // r = t*256+b, t in [0,31)
    int t = r >> 8, b = r & 255;
    bool act = (t < NT) && (b < cnt[t]);
    float4* row = (float4*)(out + (size_t)b * PRED_B + (size_t)t * NV);
    int tid = threadIdx.x;
    if (act) {
        int pos = start[t] + b;
        float lse = logf(rowsum[pos]);
        const uint4* lrow = (const uint4*)(logitb + (size_t)pos * NV);
        for (int v8 = tid; v8 < NV / 8; v8 += 256) {
            uint4 u = lrow[v8];
            float4 a, c;
            a.x = bf2f((unsigned short)u.x) - lse;
            a.y = bf2f((unsigned short)(u.x >> 16)) - lse;
            a.z = bf2f((unsigned short)u.y) - lse;
            a.w = bf2f((unsigned short)(u.y >> 16)) - lse;
            c.x = bf2f((unsigned short)u.z) - lse;
            c.y = bf2f((unsigned short)(u.z >> 16)) - lse;
            c.z = bf2f((unsigned short)u.w) - lse;
            c.w = bf2f((unsigned short)(u.w >> 16)) - lse;
            row[v8 * 2] = a;
            row[v8 * 2 + 1] = c;
        }
    } else {
        float4 z = make_float4(0.f, 0.f, 0.f, 0.f);
        for (int v4 = tid; v4 < NV / 4; v4 += 256) row[v4] = z;
    }
}

extern "C" void kernel_launch(void* const* d_in, const int* in_sizes, int n_in,
                              void* d_out, int out_size, void* d_ws, size_t ws_size,
                              hipStream_t stream) {
    const float* gimg  = (const float*)d_in[0];
    const int*   w_in  = (const int*)d_in[1];
    const int*   lens  = (const int*)d_in[2];
    const float* emb   = (const float*)d_in[3];
    const float* W_ih  = (const float*)d_in[4];
    const float* W_hh  = (const float*)d_in[5];
    const float* b_ih  = (const float*)d_in[6];
    const float* b_hh  = (const float*)d_in[7];
    const float* W_out = (const float*)d_in[8];
    const float* b_out = (const float*)d_in[9];
    float* out = (float*)d_out;

    char* p = (char*)d_ws;
    auto alloc = [&](size_t bytes) -> char* {
        char* r = p;
        p += (bytes + 255) & ~(size_t)255;
        return r;
    };
    int*   order   = (int*)alloc(NB * 4);
    int*   wsort   = (int*)alloc(NB * ML * 4);
    int*   cnt     = (int*)alloc(NT * 4);
    int*   start   = (int*)alloc((NT + 1) * 4);
    int*   flags   = (int*)alloc(256 * 4);
    int*   rowlist = (int*)alloc((size_t)NT * NB * 4);
    int*   rowwc   = (int*)alloc((size_t)NT * NB * 4);
    float* gx      = (float*)alloc((size_t)NB * NG * 4);
    float* rowsum  = (float*)alloc((size_t)NT * NB * 4);
    unsigned short* g_sb   = (unsigned short*)alloc((size_t)NB * NE * 2);
    unsigned short* hx     = (unsigned short*)alloc((size_t)2 * 16 * 16384);
    unsigned short* h_allc = (unsigned short*)alloc((size_t)NT * NB * NH * 2);
    unsigned short* Wimg2  = (unsigned short*)alloc((size_t)NG * NH * 2);
    unsigned short* Wxl    = (unsigned short*)alloc((size_t)NG * NE * 2);
    unsigned short* Wxb    = (unsigned short*)alloc((size_t)NG * NE * 2);
    unsigned short* Wob    = (unsigned short*)alloc((size_t)NV * NH * 2);
    unsigned short* embb   = (unsigned short*)alloc((size_t)NV * NE * 2);
    unsigned short* gallc  = (unsigned short*)alloc((size_t)NT * NB * NG * 2);
    unsigned short* logitb = (unsigned short*)alloc((size_t)NT * NB * NV * 2);
    int* nact = start + NT;   // n_active lives at start[30]

    sort_k<<<1, 256, 0, stream>>>(lens, order, cnt, start, flags, out + OFF_DEC);
    gather_k<<<NB, 256, 0, stream>>>(gimg, w_in, order, cnt, start,
                                     g_sb, wsort, rowlist, rowwc, rowsum, out + OFF_TGT);
    prep_k<<<12560, 256, 0, stream>>>(W_ih, W_hh, W_out, emb, Wxl, Wxb, Wob, embb, Wimg2);

    // gx = g_sb @ Wxl^T + b_ih + b_hh     (256 x 2048, K=512, fp32 out)
    gxgemm<<<dim3(NG / 128, NB / 128), 256, 0, stream>>>(g_sb, Wxl, b_ih, b_hh, gx);

    // gallc[pos][d][q] = bf16( emb[rowwc[pos]] @ Wxb^T + gx[b] )   (n_active x 2048)
    pgemm<1, 0><<<dim3(NT * NB / 128, NG / 128), 256, 0, stream>>>(
        nullptr, rowwc, embb, Wxb, NG, nact, gx, rowlist, gallc, nullptr);

    // fused 30-step recurrence: W-resident, single-writer flag sync (coop)
    {
        void* cargs[] = { (void*)&Wimg2, (void*)&gallc, (void*)&hx, (void*)&h_allc,
                          (void*)&flags, (void*)&cnt, (void*)&start };
        (void)hipLaunchCooperativeKernel((void*)lstmy_k, dim3(256), dim3(256), cargs, 0, stream);
    }

    // logits (bf16 compact) = h_allc @ Wob^T + b_out; rowsum exp-atomics
    pgemm<0, 1><<<dim3(NT * NB / 128, (NV + 127) / 128), 256, 0, stream>>>(
        h_allc, nullptr, nullptr, Wob, NV, nact, b_out, rowlist, logitb, rowsum);

    norm_k<<<(NT + 1) * NB, 256, 0, stream>>>(out, logitb, rowsum, cnt, start);
}